// Round 13
// baseline (1236.384 us; speedup 1.0000x reference)
//
#include <hip/hip_runtime.h>
#include <hip/hip_bf16.h>

#define B_    8
#define N_    1024
#define F_    128
#define G_    64
#define EC    2
#define NHD   4
#define NE    16384
#define L0_   256
#define ALPHA_ 0.5f
#define EPS_   1e-5f
#define SLOPE_ 0.01f
#define ROWS  (B_*N_)      // 8192
#define C1    (NHD*EC*G_)  // 512

typedef __attribute__((ext_vector_type(8))) short s8bf;   // 8 bf16 (4 VGPRs)
typedef __attribute__((ext_vector_type(4))) float f32x4;  // MFMA accumulator

__device__ __forceinline__ float ldv(const float* p, size_t i) { return p[i]; }
__device__ __forceinline__ float ldv(const __hip_bfloat16* p, size_t i) {
  unsigned short u = *(const unsigned short*)&p[i];
  return __uint_as_float((unsigned)u << 16);
}
__device__ __forceinline__ unsigned short f2b(float f) {   // RNE f32 -> bf16
  unsigned u = __float_as_uint(f);
  u = (u + 0x7FFFu + ((u >> 16) & 1u)) >> 16;
  return (unsigned short)u;
}
__device__ __forceinline__ float b2f(unsigned short u) {
  return __uint_as_float((unsigned)u << 16);
}
__device__ __forceinline__ float wmaxf(float v) {
#pragma unroll
  for (int o = 32; o; o >>= 1) v = fmaxf(v, __shfl_xor(v, o, 64));
  return v;
}
__device__ __forceinline__ float wsumf(float v) {
#pragma unroll
  for (int o = 32; o; o >>= 1) v += __shfl_xor(v, o, 64);
  return v;
}
__device__ __forceinline__ unsigned short cvt_at(const void* p, size_t i, int isf) {
  return isf ? f2b(((const float*)p)[i]) : ((const unsigned short*)p)[i];
}

// ---- device-scope grid barrier (256 co-resident blocks; proven round 12) --
__device__ __forceinline__ void gbar(int* cnt) {
  __syncthreads();
  __threadfence();                         // release
  if (threadIdx.x == 0) {
    atomicAdd(cnt, 1);
    while (atomicAdd(cnt, 0) < 256) __builtin_amdgcn_s_sleep(2);
  }
  __syncthreads();
  __threadfence();                         // acquire
}

// ---- unified MFMA core: 16 x NC*16 tile per wave; A bf16-direct or f32+BN -
template <int K, int NC, int MODE, typename TA>
__device__ __forceinline__ void mfma_core_u(const TA* __restrict__ Araw,
                                            const float* sum, const float* ssq,
                                            const unsigned short* __restrict__ Wb,
                                            int r0, int c0, f32x4* acc) {
  int lane = threadIdx.x & 63; int qd = lane >> 4, c15 = lane & 15;
  constexpr int RS = K / 8;
  const s8bf* bp = (const s8bf*)Wb + (size_t)(c0 + c15) * RS + qd;
#pragma unroll
  for (int ks = 0; ks < K / 32; ++ks) {
    s8bf a;
    if constexpr (sizeof(TA) == 2) {
      const s8bf* ap = (const s8bf*)Araw + (size_t)(r0 + c15) * RS + qd;
      a = ap[ks * 4];
    } else {
      const float* ap = (const float*)Araw + (size_t)(r0 + c15) * K + qd * 8 + ks * 32;
      float av[8];
      *(float4*)&av[0] = *(const float4*)ap;
      *(float4*)&av[4] = *(const float4*)(ap + 4);
#pragma unroll
      for (int j = 0; j < 8; ++j) {
        float y = av[j];
        if (MODE) {
          int c = qd * 8 + ks * 32 + j;
          float mean = sum[c] * (1.f / ROWS);
          float var = ssq[c] * (1.f / ROWS) - mean * mean;
          y = (y - mean) * rsqrtf(var + EPS_);
          if (MODE == 2) y = (y > 0.f) ? y : (expf(y) - 1.f);
        }
        a[j] = (short)f2b(y);
      }
    }
#pragma unroll
    for (int nc = 0; nc < NC; ++nc) {
      s8bf b = bp[(size_t)nc * 16 * RS + ks * 4];
      acc[nc] = __builtin_amdgcn_mfma_f32_16x16x32_bf16(a, b, acc[nc], 0, 0, 0);
    }
  }
}

// ---- mega kernel v2: 256 blocks x 1024 threads (4 waves/SIMD restored) ----
__global__ __launch_bounds__(1024) void k_mega(
    const int* A, const void* X, const void* Ws, const void* Wq, const void* Wv,
    const void* We1, const void* Wl0, const void* Wl1,
    int* flag, int* fill, int* colbuf,
    unsigned short* Wsb, unsigned short* We1b, unsigned short* Wl1b, unsigned short* Wl0b,
    float* q, float* v, unsigned short* Whb, float* S, unsigned short* Hcatb,
    float* T4, float* Z0, float* T6, float* stats, void* out, int* bars) {
  __shared__ int s_col[16][64];
  __shared__ int s_cnt[16][64];
  int tid = threadIdx.x, lane = tid & 63, w = tid >> 6;       // w: 0..15
  int gtid = blockIdx.x * 1024 + tid;                          // 0..262143
  int wid = blockIdx.x * 16 + w;                               // 0..4095
  int qd = lane >> 4, c15 = lane & 15;
  float* sum1 = stats,       *ssq1 = stats + 128;
  float* sum2 = stats + 256, *ssq2 = stats + 512;
  float* sum3 = stats + 768, *ssq3 = stats + 896;

  // ---- S0: dtype detect (proven round 2) + adjacency scatter --------------
  {
    const unsigned short* Xu = (const unsigned short*)X;
    unsigned short u = Xu[gtid];
    if ((u & 0x7F80u) == 0x7F80u) atomicOr(flag, 1);
    int be = gtid >> 14, ei = gtid & (NE - 1);                 // 262144 = 16*NE
    int row = A[(size_t)(be * 2) * NE + ei];
    int col = A[(size_t)(be * 2 + 1) * NE + ei];
    int p = atomicAdd(&fill[be * N_ + row], 1);
    if (p < 64) colbuf[((size_t)(be * N_ + row)) * 64 + p] = col;
  }
  gbar(bars + 0);
  int isf = *flag;

  // ---- S1: weight conversions + q/v projections ---------------------------
  {
    if (gtid < 196608) {
      int item = gtid;
      if (item < 65536) { We1b[item] = cvt_at(We1, item, isf); }
      else if (item < 98304) { int k = item - 65536; Wl1b[k] = cvt_at(Wl1, k, isf); }
      else if (item < 131072) { int k = item - 98304; Wl0b[k] = cvt_at(Wl0, k, isf); }
      else { int k = item - 131072; int eh = k >> 13, rem = k & 8191;
             int g = rem >> 7, f = rem & 127;
             Wsb[eh * 8192 + g * 128 + f] = cvt_at(Ws, (size_t)eh * 8192 + f * 64 + g, isf); }
    }
    int grp = gtid >> 4, fl = gtid & 15;        // 16384 groups x 4 rows
#pragma unroll
    for (int j = 0; j < 4; ++j) {
      int r = grp * 4 + j;
      int n = r & (N_ - 1); int beh = r >> 10; int be = beh >> 2, h = beh & 3;
      int b = be >> 1, e = be & 1;
      float dq = 0.f, dv = 0.f;
      if (isf) {
        const float* xr = (const float*)X + (size_t)(b * N_ + n) * F_ + fl * 8;
        const float* wq = (const float*)Wq + (e * NHD + h) * F_ + fl * 8;
        const float* wv = (const float*)Wv + (e * NHD + h) * F_ + fl * 8;
#pragma unroll
        for (int t = 0; t < 8; ++t) { float x = xr[t]; dq += x * wq[t]; dv += x * wv[t]; }
      } else {
        const __hip_bfloat16* xr = (const __hip_bfloat16*)X + (size_t)(b * N_ + n) * F_ + fl * 8;
        const __hip_bfloat16* wq = (const __hip_bfloat16*)Wq + (e * NHD + h) * F_ + fl * 8;
        const __hip_bfloat16* wv = (const __hip_bfloat16*)Wv + (e * NHD + h) * F_ + fl * 8;
#pragma unroll
        for (int t = 0; t < 8; ++t) { float x = ldv(xr, t); dq += x * ldv(wq, t); dv += x * ldv(wv, t); }
      }
#pragma unroll
      for (int o = 1; o < 16; o <<= 1) { dq += __shfl_xor(dq, o, 64); dv += __shfl_xor(dv, o, 64); }
      if (fl == 0) { q[r] = dq; v[r] = dv; }
    }
  }
  gbar(bars + 1);

  // ---- S2: Wh projection (MFMA) -> bf16 Whb + column-sum S (4096 tiles) ---
  {
    int tile = wid;                             // 512 r-tiles x 8 eh
    int eh = tile & 7, r0 = (tile >> 3) * 16;
    f32x4 acc[4] = {{0,0,0,0},{0,0,0,0},{0,0,0,0},{0,0,0,0}};
    if (isf) mfma_core_u<128, 4, 0, float>((const float*)X, nullptr, nullptr,
                                           Wsb + eh * 8192, r0, 0, acc);
    else     mfma_core_u<128, 4, 0, unsigned short>((const unsigned short*)X, nullptr, nullptr,
                                                    Wsb + eh * 8192, r0, 0, acc);
    int b = r0 >> 10; int beh = b * 8 + eh;
    unsigned short* WhB = Whb + ((size_t)beh * N_ + (r0 & (N_ - 1))) * G_;
#pragma unroll
    for (int nc = 0; nc < 4; ++nc) {
      float s = 0.f;
#pragma unroll
      for (int i = 0; i < 4; ++i) {
        float o = acc[nc][i];
        WhB[(size_t)(qd * 4 + i) * G_ + nc * 16 + c15] = f2b(o);
        s += o;
      }
      s += __shfl_xor(s, 16, 64); s += __shfl_xor(s, 32, 64);
      if (lane < 16) atomicAdd(&S[(size_t)beh * G_ + nc * 16 + lane], s);
    }
  }
  gbar(bars + 2);

  // ---- S3: sparse attention (XCD-local be; 4 n per wave) ------------------
  {
    int x = blockIdx.x & 7, jj = blockIdx.x >> 3;   // 16 blocks per be, same XCD
    int be = (x << 1) | (jj >> 4);
    int b = be >> 1, e = be & 1;
    int nb = (jj & 15) * 64 + w * 4;
    int eg = lane >> 4, g4 = (lane & 15) << 2;
    for (int it = 0; it < 4; ++it) {
      int n = nb + it;
      int L = fill[be * N_ + n];
      int Lc = (L > 64) ? 64 : L;
      int myc = (lane < Lc) ? colbuf[((size_t)(be * N_ + n)) * 64 + lane] : -1;
      int cct = 0, firstk = 64;
      for (int k = 0; k < Lc; ++k) {
        int ck = __shfl(myc, k, 64);
        if (myc >= 0 && ck == myc) { cct++; if (k < firstk) firstk = k; }
      }
      bool act = (lane < Lc) && (firstk == lane);
      unsigned long long mask = __ballot(act);
      int pos = __popcll(mask & ((1ull << lane) - 1ull));
      s_col[w][lane] = 0; s_cnt[w][lane] = 0;
      if (act) { s_col[w][pos] = myc; s_cnt[w][pos] = cct; }
      int Ld = __popcll(mask);
      int colc = s_col[w][lane];        // same-wave DS ordering: no barrier
      int cntc = s_cnt[w][lane];
      size_t outb = ((size_t)(b * N_ + n)) * C1 + e * G_ + g4;
      float fN = (float)(N_ - Ld);
#pragma unroll
      for (int h = 0; h < 4; ++h) {
        int beh = (be << 2) | h;
        float qn = q[beh * N_ + n];
        float sc = -1e30f;
        if (lane < Ld) {
          float t = qn * v[beh * N_ + colc] * (float)cntc;
          sc = (t >= 0.f) ? t : SLOPE_ * t;
        }
        float M = fmaxf(0.f, wmaxf(sc));
        float Ej = (lane < Ld) ? expf(sc - M) : 0.f;
        float sumE = wsumf(Ej);
        float em = expf(-M);
        float Z = fN * em + sumE;
        float wgt = (lane < Ld) ? (Ej - em) / Z : 0.f;
        float4 accv = make_float4(0.f, 0.f, 0.f, 0.f);
        if (eg == 0) {
          float4 s4 = *(const float4*)&S[(size_t)beh * G_ + g4];
          float sca = em / Z;
          accv.x = sca * s4.x; accv.y = sca * s4.y; accv.z = sca * s4.z; accv.w = sca * s4.w;
        }
        const unsigned short* WhB = Whb + (size_t)beh * N_ * G_;
        for (int k0 = 0; k0 < Ld; k0 += 4) {
          int kk = k0 + eg;
          float wk = __shfl(wgt, kk, 64);
          int ck = __shfl(colc, kk, 64);
          ushort4 xu = *(const ushort4*)&WhB[(size_t)ck * G_ + g4];
          accv.x += wk * b2f(xu.x); accv.y += wk * b2f(xu.y);
          accv.z += wk * b2f(xu.z); accv.w += wk * b2f(xu.w);
        }
        accv.x += __shfl_xor(accv.x, 16, 64); accv.y += __shfl_xor(accv.y, 16, 64);
        accv.z += __shfl_xor(accv.z, 16, 64); accv.w += __shfl_xor(accv.w, 16, 64);
        accv.x += __shfl_xor(accv.x, 32, 64); accv.y += __shfl_xor(accv.y, 32, 64);
        accv.z += __shfl_xor(accv.z, 32, 64); accv.w += __shfl_xor(accv.w, 32, 64);
        if (lane < 16) {
          ushort4 o;
          o.x = f2b(accv.x); o.y = f2b(accv.y); o.z = f2b(accv.z); o.w = f2b(accv.w);
          *(ushort4*)&Hcatb[outb + (size_t)h * (EC * G_)] = o;
        }
      }
    }
  }
  gbar(bars + 3);

  // ---- S4: mm1 (MFMA 16x16, 4096 tiles): T4 = 0.5*relu+0.5*X; stats1 ------
  {
    int tile = wid;                             // 512 r x 8 c16
    int r0 = (tile >> 3) * 16, c0 = (tile & 7) * 16;
    f32x4 acc[1] = {{0,0,0,0}};
    mfma_core_u<512, 1, 0, unsigned short>(Hcatb, nullptr, nullptr, We1b, r0, c0, acc);
    int cc = c0 + c15;
    float s = 0.f, s2 = 0.f;
#pragma unroll
    for (int i = 0; i < 4; ++i) {
      int rr = r0 + qd * 4 + i;
      float o = fmaxf(acc[0][i], 0.f);
      float xv = isf ? ldv((const float*)X, (size_t)rr * F_ + cc)
                     : ldv((const __hip_bfloat16*)X, (size_t)rr * F_ + cc);
      o = 0.5f * o + 0.5f * xv;
      T4[(size_t)rr * F_ + cc] = o;
      s += o; s2 += o * o;
    }
    s += __shfl_xor(s, 16, 64); s += __shfl_xor(s, 32, 64);
    s2 += __shfl_xor(s2, 16, 64); s2 += __shfl_xor(s2, 32, 64);
    if (lane < 16) {
      atomicAdd(&sum1[c0 + lane], s);
      atomicAdd(&ssq1[c0 + lane], s2);
    }
  }
  gbar(bars + 4);

  // ---- S5: lin0 (MFMA 16x32, fused bn1 on A, 4096 tiles): Z0; stats2 ------
  {
    int tile = wid;                             // 512 r x 8 c32
    int r0 = (tile >> 3) * 16, c0 = (tile & 7) * 32;
    f32x4 acc[2] = {{0,0,0,0},{0,0,0,0}};
    mfma_core_u<128, 2, 1, float>(T4, sum1, ssq1, Wl0b, r0, c0, acc);
#pragma unroll
    for (int nc = 0; nc < 2; ++nc) {
      int cc = c0 + nc * 16 + c15;
      float s = 0.f, s2 = 0.f;
#pragma unroll
      for (int i = 0; i < 4; ++i) {
        int rr = r0 + qd * 4 + i;
        float o = acc[nc][i];
        Z0[(size_t)rr * L0_ + cc] = o;
        s += o; s2 += o * o;
      }
      s += __shfl_xor(s, 16, 64); s += __shfl_xor(s, 32, 64);
      s2 += __shfl_xor(s2, 16, 64); s2 += __shfl_xor(s2, 32, 64);
      if (lane < 16) {
        atomicAdd(&sum2[c0 + nc * 16 + lane], s);
        atomicAdd(&ssq2[c0 + nc * 16 + lane], s2);
      }
    }
  }
  gbar(bars + 5);

  // ---- S6: lin1 (MFMA 16x16, fused elu(bn2) on A, 4096 tiles): T6; stats3 -
  {
    int tile = wid;                             // 512 r x 8 c16
    int r0 = (tile >> 3) * 16, c0 = (tile & 7) * 16;
    f32x4 acc[1] = {{0,0,0,0}};
    mfma_core_u<256, 1, 2, float>(Z0, sum2, ssq2, Wl1b, r0, c0, acc);
    int cc = c0 + c15;
    float mean = sum1[cc] * (1.f / ROWS);
    float var = ssq1[cc] * (1.f / ROWS) - mean * mean;
    float rs = rsqrtf(var + EPS_);
    float s = 0.f, s2 = 0.f;
#pragma unroll
    for (int i = 0; i < 4; ++i) {
      int rr = r0 + qd * 4 + i;
      float o = acc[0][i] + (T4[(size_t)rr * F_ + cc] - mean) * rs;
      T6[(size_t)rr * F_ + cc] = o;
      s += o; s2 += o * o;
    }
    s += __shfl_xor(s, 16, 64); s += __shfl_xor(s, 32, 64);
    s2 += __shfl_xor(s2, 16, 64); s2 += __shfl_xor(s2, 32, 64);
    if (lane < 16) {
      atomicAdd(&sum3[c0 + lane], s);
      atomicAdd(&ssq3[c0 + lane], s2);
    }
  }
  gbar(bars + 6);

  // ---- S7: output BN3 ------------------------------------------------------
  {
    int e0 = gtid * 4;                          // 1M elements, 1 float4/thread
    float4 xv = *(const float4*)&T6[e0];
    float y[4];
    float* xp = &xv.x;
#pragma unroll
    for (int j = 0; j < 4; ++j) {
      int c = (e0 + j) & (F_ - 1);
      float mean = sum3[c] * (1.f / ROWS);
      float var = ssq3[c] * (1.f / ROWS) - mean * mean;
      y[j] = (xp[j] - mean) * rsqrtf(var + EPS_);
    }
    if (isf) {
      *(float4*)&((float*)out)[e0] = make_float4(y[0], y[1], y[2], y[3]);
    } else {
      ushort4 o;
      o.x = f2b(y[0]); o.y = f2b(y[1]); o.z = f2b(y[2]); o.w = f2b(y[3]);
      *(ushort4*)&((__hip_bfloat16*)out)[e0] = o;
    }
  }
}

// ---------------------------------------------------------------------------
extern "C" void kernel_launch(void* const* d_in, const int* in_sizes, int n_in,
                              void* d_out, int out_size, void* d_ws, size_t ws_size,
                              hipStream_t stream) {
  const int* A    = (const int*)d_in[0];
  const void* X   = d_in[1];
  const void* Ws  = d_in[2];
  const void* Wq  = d_in[3];
  const void* Wv  = d_in[4];
  const void* We1 = d_in[5];
  const void* Wl0 = d_in[6];
  const void* Wl1 = d_in[7];

  char* ws = (char*)d_ws;
  size_t off = 0;
  auto alloc = [&](size_t bytes) { size_t o = off; off += (bytes + 255) & ~(size_t)255; return o; };
  size_t o_fill   = alloc(16 * N_ * 4);            // zeroed
  size_t o_stats  = alloc(1024 * 4);               // zeroed
  size_t o_flag   = alloc(256);                    // zeroed
  size_t o_S      = alloc((size_t)64 * G_ * 4);    // zeroed
  size_t o_bars   = alloc(256);                    // zeroed (7 barrier counters)
  size_t zero_bytes = off;
  size_t o_colbuf = alloc((size_t)16 * N_ * 64 * 4);     // 4 MiB
  size_t o_q      = alloc((size_t)64 * N_ * 4);
  size_t o_v      = alloc((size_t)64 * N_ * 4);
  size_t o_Whb    = alloc((size_t)64 * N_ * G_ * 2);     // 8 MiB bf16
  size_t o_Hcatb  = alloc((size_t)ROWS * C1 * 2);        // 8 MiB bf16
  size_t o_T4     = alloc((size_t)ROWS * F_ * 4);
  size_t o_T6     = alloc((size_t)ROWS * F_ * 4);
  size_t o_Z0     = alloc((size_t)ROWS * L0_ * 4);
  size_t o_Wsb    = alloc((size_t)8 * G_ * F_ * 2);
  size_t o_We1b   = alloc((size_t)F_ * C1 * 2);
  size_t o_Wl1b   = alloc((size_t)F_ * L0_ * 2);
  size_t o_Wl0b   = alloc((size_t)L0_ * F_ * 2);

  int*   fill   = (int*)(ws + o_fill);
  float* stats  = (float*)(ws + o_stats);
  int*   flag   = (int*)(ws + o_flag);
  float* S      = (float*)(ws + o_S);
  int*   bars   = (int*)(ws + o_bars);
  int*   colbuf = (int*)(ws + o_colbuf);
  float* q      = (float*)(ws + o_q);
  float* v      = (float*)(ws + o_v);
  unsigned short* Whb   = (unsigned short*)(ws + o_Whb);
  unsigned short* Hcatb = (unsigned short*)(ws + o_Hcatb);
  float* T4     = (float*)(ws + o_T4);
  float* T6     = (float*)(ws + o_T6);
  float* Z0     = (float*)(ws + o_Z0);
  unsigned short* Wsb   = (unsigned short*)(ws + o_Wsb);
  unsigned short* We1b  = (unsigned short*)(ws + o_We1b);
  unsigned short* Wl1b  = (unsigned short*)(ws + o_Wl1b);
  unsigned short* Wl0b  = (unsigned short*)(ws + o_Wl0b);

  hipMemsetAsync(ws, 0, zero_bytes, stream);

  k_mega<<<256, 1024, 0, stream>>>(A, X, Ws, Wq, Wv, We1, Wl0, Wl1,
                                   flag, fill, colbuf,
                                   Wsb, We1b, Wl1b, Wl0b,
                                   q, v, Whb, S, Hcatb,
                                   T4, Z0, T6, stats, d_out, bars);

  (void)in_sizes; (void)n_in; (void)out_size; (void)ws_size;
}

// Round 14
// 212.647 us; speedup vs baseline: 5.8143x; 5.8143x over previous
//
#include <hip/hip_runtime.h>
#include <hip/hip_bf16.h>

#define B_    8
#define N_    1024
#define F_    128
#define G_    64
#define EC    2
#define NHD   4
#define NE    16384
#define L0_   256
#define ALPHA_ 0.5f
#define EPS_   1e-5f
#define SLOPE_ 0.01f
#define ROWS  (B_*N_)      // 8192
#define C1    (NHD*EC*G_)  // 512

typedef __attribute__((ext_vector_type(8))) short s8bf;   // 8 bf16 (4 VGPRs)
typedef __attribute__((ext_vector_type(4))) float f32x4;  // MFMA accumulator

__device__ __forceinline__ float ldv(const float* p, size_t i) { return p[i]; }
__device__ __forceinline__ float ldv(const __hip_bfloat16* p, size_t i) {
  unsigned short u = *(const unsigned short*)&p[i];
  return __uint_as_float((unsigned)u << 16);
}
__device__ __forceinline__ unsigned short f2b(float f) {   // RNE f32 -> bf16
  unsigned u = __float_as_uint(f);
  u = (u + 0x7FFFu + ((u >> 16) & 1u)) >> 16;
  return (unsigned short)u;
}
__device__ __forceinline__ float b2f(unsigned short u) {
  return __uint_as_float((unsigned)u << 16);
}

__device__ __forceinline__ float wmaxf(float v) {
#pragma unroll
  for (int o = 32; o; o >>= 1) v = fmaxf(v, __shfl_xor(v, o, 64));
  return v;
}
__device__ __forceinline__ float wsumf(float v) {
#pragma unroll
  for (int o = 32; o; o >>= 1) v += __shfl_xor(v, o, 64);
  return v;
}

// ---- prep: dtype detect (bid<512) + adjacency scatter (bid>=512) ----------
__global__ void k_prep(const unsigned short* Xu, int* flag,
                       const int* A, int* fill, int* colbuf) {
  int bid = blockIdx.x, tid = threadIdx.x;
  if (bid < 512) {                         // detect (proven round 2 — unchanged logic)
    int idx = bid * 256 + tid;
    unsigned short u = Xu[idx];
    if ((u & 0x7F80u) == 0x7F80u) atomicOr(flag, 1);
  } else {                                 // scatter: fixed-capacity row buckets
    int idx = (bid - 512) * 256 + tid;     // 16*NE
    int be = idx >> 14, i = idx & (NE - 1);
    int row = A[(size_t)(be * 2) * NE + i];
    int col = A[(size_t)(be * 2 + 1) * NE + i];
    int p = atomicAdd(&fill[be * N_ + row], 1);
    if (p < 64) colbuf[((size_t)(be * N_ + row)) * 64 + p] = col;
  }
}

// ---- cvt2: weight conversions + 16-lane-group q/v projections -------------
__device__ __forceinline__ unsigned short cvt_at(const void* p, size_t i, int isf) {
  return isf ? f2b(((const float*)p)[i]) : ((const unsigned short*)p)[i];
}
template <typename T>
__device__ __forceinline__ void proj_qv16(const T* X, const T* Wq, const T* Wv,
                                          float* q, float* v, int pb) {
  int tid = threadIdx.x, lane = tid & 63, w = tid >> 6;
  int sub = lane >> 4, fl = lane & 15;
  int r = pb * 16 + w * 4 + sub;
  int n = r & (N_ - 1); int beh = r >> 10; int be = beh >> 2, h = beh & 3;
  int b = be >> 1, e = be & 1;
  const T* xr = X + (size_t)(b * N_ + n) * F_ + fl * 8;
  const T* wq = Wq + (e * NHD + h) * F_ + fl * 8;
  const T* wv = Wv + (e * NHD + h) * F_ + fl * 8;
  float dq = 0.f, dv = 0.f;
#pragma unroll
  for (int j = 0; j < 8; ++j) {
    float x = ldv(xr, j);
    dq += x * ldv(wq, j); dv += x * ldv(wv, j);
  }
#pragma unroll
  for (int o = 1; o < 16; o <<= 1) {
    dq += __shfl_xor(dq, o, 64); dv += __shfl_xor(dv, o, 64);
  }
  if (fl == 0) { q[r] = dq; v[r] = dv; }
}
__global__ void k_cvt2(const void* X, const void* Ws, const void* We1, const void* Wl1,
                       const void* Wl0, const void* Wq, const void* Wv,
                       unsigned short* Wsb, unsigned short* We1b,
                       unsigned short* Wl1b, unsigned short* Wl0b,
                       float* q, float* v, const int* flag) {
  int isf = *flag;
  int bid = blockIdx.x, t = threadIdx.x;
  if (bid < 256) {                        // We1: 128*512
    int i = bid * 256 + t; We1b[i] = cvt_at(We1, i, isf);
  } else if (bid < 384) {                 // Wl1: 128*256
    int i = (bid - 256) * 256 + t; Wl1b[i] = cvt_at(Wl1, i, isf);
  } else if (bid < 512) {                 // Wl0: 256*128
    int i = (bid - 384) * 256 + t; Wl0b[i] = cvt_at(Wl0, i, isf);
  } else if (bid < 768) {                 // Ws: [eh][f][g] -> Wsb [eh][g][f]
    int i = (bid - 512) * 256 + t;        // 0..65535
    int eh = i >> 13, rem = i & 8191;
    int g = rem >> 7, f = rem & 127;
    Wsb[eh * 8192 + g * 128 + f] = cvt_at(Ws, (size_t)eh * 8192 + f * 64 + g, isf);
  } else {                                // q/v projections: 4096 blocks, 16 r each
    int pb = bid - 768;
    if (isf) proj_qv16<float>((const float*)X, (const float*)Wq, (const float*)Wv, q, v, pb);
    else     proj_qv16<__hip_bfloat16>((const __hip_bfloat16*)X, (const __hip_bfloat16*)Wq,
                                       (const __hip_bfloat16*)Wv, q, v, pb);
  }
}

// ---- unified MFMA core: 16xNC*16 tile per wave; A bf16-direct or f32+BN ---
template <int K, int NC, int MODE, typename TA>
__device__ __forceinline__ void mfma_core_u(const TA* __restrict__ Araw,
                                            const float* sum, const float* ssq,
                                            const unsigned short* __restrict__ Wb,
                                            int r0, int c0, f32x4* acc) {
  int lane = threadIdx.x & 63; int q = lane >> 4, c15 = lane & 15;
  constexpr int RS = K / 8;
  const s8bf* bp = (const s8bf*)Wb + (size_t)(c0 + c15) * RS + q;
#pragma unroll
  for (int ks = 0; ks < K / 32; ++ks) {
    s8bf a;
    if constexpr (sizeof(TA) == 2) {
      const s8bf* ap = (const s8bf*)Araw + (size_t)(r0 + c15) * RS + q;
      a = ap[ks * 4];
    } else {
      const float* ap = (const float*)Araw + (size_t)(r0 + c15) * K + q * 8 + ks * 32;
      float av[8];
      *(float4*)&av[0] = *(const float4*)ap;
      *(float4*)&av[4] = *(const float4*)(ap + 4);
#pragma unroll
      for (int j = 0; j < 8; ++j) {
        float y = av[j];
        if (MODE) {
          int c = q * 8 + ks * 32 + j;
          float mean = sum[c] * (1.f / ROWS);
          float var = ssq[c] * (1.f / ROWS) - mean * mean;
          y = (y - mean) * rsqrtf(var + EPS_);
          if (MODE == 2) y = (y > 0.f) ? y : (expf(y) - 1.f);
        }
        a[j] = (short)f2b(y);
      }
    }
#pragma unroll
    for (int nc = 0; nc < NC; ++nc) {
      s8bf b = bp[(size_t)nc * 16 * RS + ks * 4];
      acc[nc] = __builtin_amdgcn_mfma_f32_16x16x32_bf16(a, b, acc[nc], 0, 0, 0);
    }
  }
}

// ---- Wh projection (MFMA, reads X directly) -> bf16 Wh + column-sum S -----
__global__ __launch_bounds__(256) void k_whm(const void* X, const unsigned short* Wsb,
                                             unsigned short* Whb, float* S,
                                             const int* flag) {
  int w = threadIdx.x >> 6;
  int r0 = (blockIdx.x * 4 + w) * 16; int eh = blockIdx.y;
  f32x4 acc[4] = {{0,0,0,0},{0,0,0,0},{0,0,0,0},{0,0,0,0}};
  if (*flag)
    mfma_core_u<128, 4, 0, float>((const float*)X, nullptr, nullptr,
                                  Wsb + eh * 8192, r0, 0, acc);
  else
    mfma_core_u<128, 4, 0, unsigned short>((const unsigned short*)X, nullptr, nullptr,
                                           Wsb + eh * 8192, r0, 0, acc);
  int lane = threadIdx.x & 63, q = lane >> 4, c15 = lane & 15;
  int b = r0 >> 10; int beh = b * 8 + eh;
  unsigned short* WhB = Whb + ((size_t)beh * N_ + (r0 & (N_ - 1))) * G_;
#pragma unroll
  for (int nc = 0; nc < 4; ++nc) {
    float s = 0.f;
#pragma unroll
    for (int i = 0; i < 4; ++i) {
      float o = acc[nc][i];
      WhB[(size_t)(q * 4 + i) * G_ + nc * 16 + c15] = f2b(o);
      s += o;
    }
    s += __shfl_xor(s, 16, 64); s += __shfl_xor(s, 32, 64);
    if (lane < 16) atomicAdd(&S[(size_t)beh * G_ + nc * 16 + lane], s);
  }
}

// ---- sparse attention v4 (round-10/11, passing — unchanged) ---------------
__global__ __launch_bounds__(256) void k_attn3(const float* q, const float* v,
                                               const unsigned short* Whb,
                                               const float* S, const int* fill,
                                               const int* colbuf, unsigned short* Hcatb) {
  int tid = threadIdx.x, lane = tid & 63, w = tid >> 6;
  int xcd = blockIdx.x & 7, j = blockIdx.x >> 3;
  int be = (xcd << 1) | (j & 1);
  int n = (j >> 1) * 4 + w;
  int b = be >> 1, e = be & 1;
  int L = fill[be * N_ + n];
  int Lc = (L > 64) ? 64 : L;
  int myc = (lane < Lc) ? colbuf[((size_t)(be * N_ + n)) * 64 + lane] : -1;
  int cct = 0, firstk = 64;
  for (int k = 0; k < Lc; ++k) {
    int ck = __shfl(myc, k, 64);
    if (myc >= 0 && ck == myc) { cct++; if (k < firstk) firstk = k; }
  }
  bool act = (lane < Lc) && (firstk == lane);
  unsigned long long mask = __ballot(act);
  int pos = __popcll(mask & ((1ull << lane) - 1ull));
  __shared__ int s_col[4][64];
  __shared__ int s_cnt[4][64];
  s_col[w][lane] = 0; s_cnt[w][lane] = 0;
  if (act) { s_col[w][pos] = myc; s_cnt[w][pos] = cct; }
  int Ld = __popcll(mask);
  int colc = s_col[w][lane];          // same-wave DS ordering: no barrier needed
  int cntc = s_cnt[w][lane];
  int eg = lane >> 4, g4 = (lane & 15) << 2;
  size_t outb = ((size_t)(b * N_ + n)) * C1 + e * G_ + g4;
  float fN = (float)(N_ - Ld);
#pragma unroll
  for (int h = 0; h < 4; ++h) {
    int beh = (be << 2) | h;
    float qn = q[beh * N_ + n];
    float sc = -1e30f;
    if (lane < Ld) {
      float t = qn * v[beh * N_ + colc] * (float)cntc;
      sc = (t >= 0.f) ? t : SLOPE_ * t;
    }
    float M = fmaxf(0.f, wmaxf(sc));
    float Ej = (lane < Ld) ? expf(sc - M) : 0.f;
    float sumE = wsumf(Ej);
    float em = expf(-M);
    float Z = fN * em + sumE;
    float wgt = (lane < Ld) ? (Ej - em) / Z : 0.f;
    float4 accv = make_float4(0.f, 0.f, 0.f, 0.f);
    if (eg == 0) {
      float4 s4 = *(const float4*)&S[(size_t)beh * G_ + g4];
      float sca = em / Z;
      accv.x = sca * s4.x; accv.y = sca * s4.y; accv.z = sca * s4.z; accv.w = sca * s4.w;
    }
    const unsigned short* WhB = Whb + (size_t)beh * N_ * G_;
    for (int k0 = 0; k0 < Ld; k0 += 4) {
      int kk = k0 + eg;
      float wk = __shfl(wgt, kk, 64);
      int ck = __shfl(colc, kk, 64);
      ushort4 xu = *(const ushort4*)&WhB[(size_t)ck * G_ + g4];
      accv.x += wk * b2f(xu.x); accv.y += wk * b2f(xu.y);
      accv.z += wk * b2f(xu.z); accv.w += wk * b2f(xu.w);
    }
    accv.x += __shfl_xor(accv.x, 16, 64); accv.y += __shfl_xor(accv.y, 16, 64);
    accv.z += __shfl_xor(accv.z, 16, 64); accv.w += __shfl_xor(accv.w, 16, 64);
    accv.x += __shfl_xor(accv.x, 32, 64); accv.y += __shfl_xor(accv.y, 32, 64);
    accv.z += __shfl_xor(accv.z, 32, 64); accv.w += __shfl_xor(accv.w, 32, 64);
    if (lane < 16) {
      ushort4 o;
      o.x = f2b(accv.x); o.y = f2b(accv.y); o.z = f2b(accv.z); o.w = f2b(accv.w);
      *(ushort4*)&Hcatb[outb + (size_t)h * (EC * G_)] = o;
    }
  }
}

// ---- mm1 (MFMA 16x32 tiles, 2048 waves): T4 = 0.5*relu(.)+0.5*X; stats1 ---
template <typename TX>
__device__ __forceinline__ void mm1_ep(f32x4* acc, const TX* X, float* T4,
                                       float* sum1, float* ssq1, int r0, int c0) {
  int lane = threadIdx.x & 63, q = lane >> 4, c15 = lane & 15;
#pragma unroll
  for (int nc = 0; nc < 2; ++nc) {
    int cc = c0 + nc * 16 + c15;
    float s = 0.f, s2 = 0.f;
#pragma unroll
    for (int i = 0; i < 4; ++i) {
      int rr = r0 + q * 4 + i;
      float o = fmaxf(acc[nc][i], 0.f);
      o = 0.5f * o + 0.5f * ldv(X, (size_t)rr * F_ + cc);
      T4[(size_t)rr * F_ + cc] = o;
      s += o; s2 += o * o;
    }
    s += __shfl_xor(s, 16, 64); s += __shfl_xor(s, 32, 64);
    s2 += __shfl_xor(s2, 16, 64); s2 += __shfl_xor(s2, 32, 64);
    if (lane < 16) {
      atomicAdd(&sum1[c0 + nc * 16 + lane], s);
      atomicAdd(&ssq1[c0 + nc * 16 + lane], s2);
    }
  }
}
__global__ __launch_bounds__(256) void k_mm1m(const unsigned short* Hcatb,
                                              const unsigned short* We1b, const void* X,
                                              float* T4, float* sum1, float* ssq1,
                                              const int* flag) {
  int w = threadIdx.x >> 6;
  int tile = blockIdx.x * 4 + w;                 // 2048 tiles
  int r0 = (tile >> 2) * 16, c0 = (tile & 3) * 32;
  f32x4 acc[2] = {{0,0,0,0},{0,0,0,0}};
  mfma_core_u<512, 2, 0, unsigned short>(Hcatb, nullptr, nullptr, We1b, r0, c0, acc);
  if (*flag) mm1_ep<float>(acc, (const float*)X, T4, sum1, ssq1, r0, c0);
  else       mm1_ep<__hip_bfloat16>(acc, (const __hip_bfloat16*)X, T4, sum1, ssq1, r0, c0);
}

// ---- lin0 (MFMA 16x32, fused bn1 on A, 4096 waves): Z0; stats2 ------------
__global__ __launch_bounds__(256) void k_lin0m(const float* T4, const float* sum1,
                                               const float* ssq1, const unsigned short* Wl0b,
                                               float* Z0, float* sum2, float* ssq2) {
  int w = threadIdx.x >> 6;
  int tile = blockIdx.x * 4 + w;                 // 4096 tiles
  int r0 = (tile >> 3) * 16, c0 = (tile & 7) * 32;
  f32x4 acc[2] = {{0,0,0,0},{0,0,0,0}};
  mfma_core_u<128, 2, 1, float>(T4, sum1, ssq1, Wl0b, r0, c0, acc);
  int lane = threadIdx.x & 63, q = lane >> 4, c15 = lane & 15;
#pragma unroll
  for (int nc = 0; nc < 2; ++nc) {
    int cc = c0 + nc * 16 + c15;
    float s = 0.f, s2 = 0.f;
#pragma unroll
    for (int i = 0; i < 4; ++i) {
      int rr = r0 + q * 4 + i;
      float o = acc[nc][i];
      Z0[(size_t)rr * L0_ + cc] = o;
      s += o; s2 += o * o;
    }
    s += __shfl_xor(s, 16, 64); s += __shfl_xor(s, 32, 64);
    s2 += __shfl_xor(s2, 16, 64); s2 += __shfl_xor(s2, 32, 64);
    if (lane < 16) {
      atomicAdd(&sum2[c0 + nc * 16 + lane], s);
      atomicAdd(&ssq2[c0 + nc * 16 + lane], s2);
    }
  }
}

// ---- lin1 (MFMA 16x32, fused elu(bn2) on A, 2048 waves): T6; stats3 -------
__global__ __launch_bounds__(256) void k_lin1m(const float* Z0, const float* sum2,
                                               const float* ssq2, const unsigned short* Wl1b,
                                               const float* T4, const float* sum1,
                                               const float* ssq1,
                                               float* T6, float* sum3, float* ssq3) {
  int w = threadIdx.x >> 6;
  int tile = blockIdx.x * 4 + w;                 // 2048 tiles
  int r0 = (tile >> 2) * 16, c0 = (tile & 3) * 32;
  f32x4 acc[2] = {{0,0,0,0},{0,0,0,0}};
  mfma_core_u<256, 2, 2, float>(Z0, sum2, ssq2, Wl1b, r0, c0, acc);
  int lane = threadIdx.x & 63, q = lane >> 4, c15 = lane & 15;
#pragma unroll
  for (int nc = 0; nc < 2; ++nc) {
    int cc = c0 + nc * 16 + c15;
    float mean = sum1[cc] * (1.f / ROWS);
    float var = ssq1[cc] * (1.f / ROWS) - mean * mean;
    float rs = rsqrtf(var + EPS_);
    float s = 0.f, s2 = 0.f;
#pragma unroll
    for (int i = 0; i < 4; ++i) {
      int rr = r0 + q * 4 + i;
      float o = acc[nc][i] + (T4[(size_t)rr * F_ + cc] - mean) * rs;
      T6[(size_t)rr * F_ + cc] = o;
      s += o; s2 += o * o;
    }
    s += __shfl_xor(s, 16, 64); s += __shfl_xor(s, 32, 64);
    s2 += __shfl_xor(s2, 16, 64); s2 += __shfl_xor(s2, 32, 64);
    if (lane < 16) {
      atomicAdd(&sum3[c0 + nc * 16 + lane], s);
      atomicAdd(&ssq3[c0 + nc * 16 + lane], s2);
    }
  }
}

__global__ void k_norm_out(const float* in, void* out, const float* sum, const float* ssq,
                           const int* flag) {
  int idx = blockIdx.x * 256 + threadIdx.x; int c = idx & (F_ - 1);
  float mean = sum[c] * (1.f / ROWS);
  float var = ssq[c] * (1.f / ROWS) - mean * mean;
  float y = (in[idx] - mean) * rsqrtf(var + EPS_);
  if (*flag) ((float*)out)[idx] = y;
  else       ((__hip_bfloat16*)out)[idx] = __float2bfloat16(y);
}

// ---------------------------------------------------------------------------
extern "C" void kernel_launch(void* const* d_in, const int* in_sizes, int n_in,
                              void* d_out, int out_size, void* d_ws, size_t ws_size,
                              hipStream_t stream) {
  const int* A    = (const int*)d_in[0];
  const void* X   = d_in[1];
  const void* Ws  = d_in[2];
  const void* Wq  = d_in[3];
  const void* Wv  = d_in[4];
  const void* We1 = d_in[5];
  const void* Wl0 = d_in[6];
  const void* Wl1 = d_in[7];

  char* ws = (char*)d_ws;
  size_t off = 0;
  auto alloc = [&](size_t bytes) { size_t o = off; off += (bytes + 255) & ~(size_t)255; return o; };
  size_t o_fill   = alloc(16 * N_ * 4);            // zeroed
  size_t o_stats  = alloc(1024 * 4);               // zeroed
  size_t o_flag   = alloc(256);                    // zeroed
  size_t o_S      = alloc((size_t)64 * G_ * 4);    // zeroed (atomic accum)
  size_t zero_bytes = off;
  size_t o_colbuf = alloc((size_t)16 * N_ * 64 * 4);     // 4 MiB
  size_t o_q      = alloc((size_t)64 * N_ * 4);
  size_t o_v      = alloc((size_t)64 * N_ * 4);
  size_t o_Whb    = alloc((size_t)64 * N_ * G_ * 2);     // 8 MiB bf16
  size_t o_Hcatb  = alloc((size_t)ROWS * C1 * 2);        // 8 MiB bf16
  size_t o_T4     = alloc((size_t)ROWS * F_ * 4);        // f32
  size_t o_T6     = alloc((size_t)ROWS * F_ * 4);
  size_t o_Z0     = alloc((size_t)ROWS * L0_ * 4);       // f32
  size_t o_Wsb    = alloc((size_t)8 * G_ * F_ * 2);
  size_t o_We1b   = alloc((size_t)F_ * C1 * 2);
  size_t o_Wl1b   = alloc((size_t)F_ * L0_ * 2);
  size_t o_Wl0b   = alloc((size_t)L0_ * F_ * 2);

  int*   fill   = (int*)(ws + o_fill);
  float* stats  = (float*)(ws + o_stats);
  int*   flag   = (int*)(ws + o_flag);
  float* S      = (float*)(ws + o_S);
  int*   colbuf = (int*)(ws + o_colbuf);
  float* q      = (float*)(ws + o_q);
  float* v      = (float*)(ws + o_v);
  unsigned short* Whb   = (unsigned short*)(ws + o_Whb);
  unsigned short* Hcatb = (unsigned short*)(ws + o_Hcatb);
  float* T4     = (float*)(ws + o_T4);
  float* T6     = (float*)(ws + o_T6);
  float* Z0     = (float*)(ws + o_Z0);
  unsigned short* Wsb   = (unsigned short*)(ws + o_Wsb);
  unsigned short* We1b  = (unsigned short*)(ws + o_We1b);
  unsigned short* Wl1b  = (unsigned short*)(ws + o_Wl1b);
  unsigned short* Wl0b  = (unsigned short*)(ws + o_Wl0b);
  float* sum1 = stats,       *ssq1 = stats + 128;
  float* sum2 = stats + 256, *ssq2 = stats + 512;
  float* sum3 = stats + 768, *ssq3 = stats + 896;

  hipMemsetAsync(ws, 0, zero_bytes, stream);

  k_prep<<<1536, 256, 0, stream>>>((const unsigned short*)X, flag, A, fill, colbuf);
  k_cvt2<<<768 + 4096, 256, 0, stream>>>(X, Ws, We1, Wl1, Wl0, Wq, Wv,
                                         Wsb, We1b, Wl1b, Wl0b, q, v, flag);
  k_whm<<<dim3(ROWS / 64, 8), 256, 0, stream>>>(X, Wsb, Whb, S, flag);
  k_attn3<<<(16 * N_) / 4, 256, 0, stream>>>(q, v, Whb, S, fill, colbuf, Hcatb);
  k_mm1m<<<512, 256, 0, stream>>>(Hcatb, We1b, X, T4, sum1, ssq1, flag);
  k_lin0m<<<1024, 256, 0, stream>>>(T4, sum1, ssq1, Wl0b, Z0, sum2, ssq2);
  k_lin1m<<<512, 256, 0, stream>>>(Z0, sum2, ssq2, Wl1b, T4, sum1, ssq1,
                                   T6, sum3, ssq3);
  k_norm_out<<<(ROWS * F_) / 256, 256, 0, stream>>>(T6, d_out, sum3, ssq3, flag);

  (void)in_sizes; (void)n_in; (void)out_size; (void)ws_size;
}

// Round 15
// 206.067 us; speedup vs baseline: 5.9999x; 1.0319x over previous
//
#include <hip/hip_runtime.h>
#include <hip/hip_bf16.h>

#define B_    8
#define N_    1024
#define F_    128
#define G_    64
#define EC    2
#define NHD   4
#define NE    16384
#define L0_   256
#define ALPHA_ 0.5f
#define EPS_   1e-5f
#define SLOPE_ 0.01f
#define ROWS  (B_*N_)      // 8192
#define C1    (NHD*EC*G_)  // 512

typedef __attribute__((ext_vector_type(8))) short s8bf;   // 8 bf16 (4 VGPRs)
typedef __attribute__((ext_vector_type(4))) float f32x4;  // MFMA accumulator

__device__ __forceinline__ float ldv(const float* p, size_t i) { return p[i]; }
__device__ __forceinline__ float ldv(const __hip_bfloat16* p, size_t i) {
  unsigned short u = *(const unsigned short*)&p[i];
  return __uint_as_float((unsigned)u << 16);
}
__device__ __forceinline__ unsigned short f2b(float f) {   // RNE f32 -> bf16
  unsigned u = __float_as_uint(f);
  u = (u + 0x7FFFu + ((u >> 16) & 1u)) >> 16;
  return (unsigned short)u;
}
__device__ __forceinline__ float b2f(unsigned short u) {
  return __uint_as_float((unsigned)u << 16);
}

__device__ __forceinline__ float wmaxf(float v) {
#pragma unroll
  for (int o = 32; o; o >>= 1) v = fmaxf(v, __shfl_xor(v, o, 64));
  return v;
}
__device__ __forceinline__ float wsumf(float v) {
#pragma unroll
  for (int o = 32; o; o >>= 1) v += __shfl_xor(v, o, 64);
  return v;
}

// ---- prep: dtype detect (bid<512) + adjacency scatter (bid>=512) ----------
__global__ void k_prep(const unsigned short* Xu, int* flag,
                       const int* A, int* fill, int* colbuf) {
  int bid = blockIdx.x, tid = threadIdx.x;
  if (bid < 512) {                         // detect (proven round 2 — unchanged logic)
    int idx = bid * 256 + tid;
    unsigned short u = Xu[idx];
    if ((u & 0x7F80u) == 0x7F80u) atomicOr(flag, 1);
  } else {                                 // scatter: fixed-capacity row buckets
    int idx = (bid - 512) * 256 + tid;     // 16*NE
    int be = idx >> 14, i = idx & (NE - 1);
    int row = A[(size_t)(be * 2) * NE + i];
    int col = A[(size_t)(be * 2 + 1) * NE + i];
    int p = atomicAdd(&fill[be * N_ + row], 1);
    if (p < 64) colbuf[((size_t)(be * N_ + row)) * 64 + p] = col;
  }
}

// ---- cvt2: weight conversions only (q/v now fused into whm via Wqvb) ------
__device__ __forceinline__ unsigned short cvt_at(const void* p, size_t i, int isf) {
  return isf ? f2b(((const float*)p)[i]) : ((const unsigned short*)p)[i];
}
__global__ void k_cvt2(const void* Ws, const void* We1, const void* Wl1,
                       const void* Wl0, const void* Wq, const void* Wv,
                       unsigned short* Wsb, unsigned short* We1b,
                       unsigned short* Wl1b, unsigned short* Wl0b,
                       unsigned short* Wqvb, const int* flag) {
  int isf = *flag;
  int bid = blockIdx.x, t = threadIdx.x;
  if (bid < 256) {                        // We1: 128*512
    int i = bid * 256 + t; We1b[i] = cvt_at(We1, i, isf);
  } else if (bid < 384) {                 // Wl1: 128*256
    int i = (bid - 256) * 256 + t; Wl1b[i] = cvt_at(Wl1, i, isf);
  } else if (bid < 512) {                 // Wl0: 256*128
    int i = (bid - 384) * 256 + t; Wl0b[i] = cvt_at(Wl0, i, isf);
  } else if (bid < 768) {                 // Ws: [eh][f][g] -> Wsb [eh][g][f]
    int i = (bid - 512) * 256 + t;        // 0..65535
    int eh = i >> 13, rem = i & 8191;
    int g = rem >> 7, f = rem & 127;
    Wsb[eh * 8192 + g * 128 + f] = cvt_at(Ws, (size_t)eh * 8192 + f * 64 + g, isf);
  } else {                                // Wqvb[c][f], c = eh*2 + {0:q,1:v}
    int i = (bid - 768) * 256 + t;        // 0..2047
    int c = i >> 7, f = i & 127;
    int eh = c >> 1;                      // eh = e*4+h
    size_t src = (size_t)eh * 128 + f;    // == e*512 + h*128 + f
    Wqvb[(size_t)c * 128 + f] = (c & 1) ? cvt_at(Wv, src, isf) : cvt_at(Wq, src, isf);
  }
}

// ---- unified MFMA core: 16xNC*16 tile per wave; A bf16-direct or f32 ------
template <int K, int NC, typename TA>
__device__ __forceinline__ void mfma_core_u(const TA* __restrict__ Araw,
                                            const unsigned short* __restrict__ Wb,
                                            int r0, int c0, f32x4* acc) {
  int lane = threadIdx.x & 63; int q = lane >> 4, c15 = lane & 15;
  constexpr int RS = K / 8;
  const s8bf* bp = (const s8bf*)Wb + (size_t)(c0 + c15) * RS + q;
#pragma unroll
  for (int ks = 0; ks < K / 32; ++ks) {
    s8bf a;
    if constexpr (sizeof(TA) == 2) {
      const s8bf* ap = (const s8bf*)Araw + (size_t)(r0 + c15) * RS + q;
      a = ap[ks * 4];
    } else {
      const float* ap = (const float*)Araw + (size_t)(r0 + c15) * K + q * 8 + ks * 32;
      float av[8];
      *(float4*)&av[0] = *(const float4*)ap;
      *(float4*)&av[4] = *(const float4*)(ap + 4);
#pragma unroll
      for (int j = 0; j < 8; ++j) a[j] = (short)f2b(av[j]);
    }
#pragma unroll
    for (int nc = 0; nc < NC; ++nc) {
      s8bf b = bp[(size_t)nc * 16 * RS + ks * 4];
      acc[nc] = __builtin_amdgcn_mfma_f32_16x16x32_bf16(a, b, acc[nc], 0, 0, 0);
    }
  }
}

// ---- MFMA core, f32 A transformed via LDS-cached mean/rs tables -----------
template <int K, int NC, int MODE>   // MODE 1: bn; 2: elu(bn)
__device__ __forceinline__ void mfma_core_t2(const float* __restrict__ Araw,
                                             const float* smean, const float* srs,
                                             const unsigned short* __restrict__ Wb,
                                             int r0, int c0, f32x4* acc) {
  int lane = threadIdx.x & 63; int q = lane >> 4, c15 = lane & 15;
  constexpr int RS = K / 8;
  const s8bf* bp = (const s8bf*)Wb + (size_t)(c0 + c15) * RS + q;
#pragma unroll
  for (int ks = 0; ks < K / 32; ++ks) {
    const float* ap = Araw + (size_t)(r0 + c15) * K + q * 8 + ks * 32;
    float av[8];
    *(float4*)&av[0] = *(const float4*)ap;
    *(float4*)&av[4] = *(const float4*)(ap + 4);
    s8bf a;
#pragma unroll
    for (int j = 0; j < 8; ++j) {
      int c = q * 8 + ks * 32 + j;
      float y = (av[j] - smean[c]) * srs[c];
      if (MODE == 2) y = (y > 0.f) ? y : (expf(y) - 1.f);
      a[j] = (short)f2b(y);
    }
    s8bf b0 = bp[ks * 4];
    acc[0] = __builtin_amdgcn_mfma_f32_16x16x32_bf16(a, b0, acc[0], 0, 0, 0);
    if (NC > 1) {
      s8bf b1 = bp[(size_t)16 * RS + ks * 4];
      acc[1] = __builtin_amdgcn_mfma_f32_16x16x32_bf16(a, b1, acc[1], 0, 0, 0);
    }
  }
}

// ---- Wh projection (MFMA) + fused q/v tile (blockIdx.y==8) ----------------
__global__ __launch_bounds__(256) void k_whm(const void* X, const unsigned short* Wsb,
                                             const unsigned short* Wqvb,
                                             unsigned short* Whb, float* S,
                                             float* q, float* v, const int* flag) {
  int w = threadIdx.x >> 6;
  int r0 = (blockIdx.x * 4 + w) * 16; int eh = blockIdx.y;
  int lane = threadIdx.x & 63, qd = lane >> 4, c15 = lane & 15;
  if (eh < 8) {
    f32x4 acc[4] = {{0,0,0,0},{0,0,0,0},{0,0,0,0},{0,0,0,0}};
    if (*flag)
      mfma_core_u<128, 4, float>((const float*)X, Wsb + eh * 8192, r0, 0, acc);
    else
      mfma_core_u<128, 4, unsigned short>((const unsigned short*)X, Wsb + eh * 8192, r0, 0, acc);
    int b = r0 >> 10; int beh = b * 8 + eh;
    unsigned short* WhB = Whb + ((size_t)beh * N_ + (r0 & (N_ - 1))) * G_;
#pragma unroll
    for (int nc = 0; nc < 4; ++nc) {
      float s = 0.f;
#pragma unroll
      for (int i = 0; i < 4; ++i) {
        float o = acc[nc][i];
        WhB[(size_t)(qd * 4 + i) * G_ + nc * 16 + c15] = f2b(o);
        s += o;
      }
      s += __shfl_xor(s, 16, 64); s += __shfl_xor(s, 32, 64);
      if (lane < 16) atomicAdd(&S[(size_t)beh * G_ + nc * 16 + lane], s);
    }
  } else {
    // q/v tile: 16 cols = 8 eh x {q,v}; col c15 -> eh=c15>>1 (=e*4+h), qv=c15&1
    f32x4 acc[1] = {{0,0,0,0}};
    if (*flag)
      mfma_core_u<128, 1, float>((const float*)X, Wqvb, r0, 0, acc);
    else
      mfma_core_u<128, 1, unsigned short>((const unsigned short*)X, Wqvb, r0, 0, acc);
    int ehq = c15 >> 1, e = ehq >> 2, h = ehq & 3;
    float* dst = (c15 & 1) ? v : q;
#pragma unroll
    for (int i = 0; i < 4; ++i) {
      int rr = r0 + qd * 4 + i;
      int b = rr >> 10, n = rr & (N_ - 1);
      int beh = ((b * 2 + e) << 2) | h;
      dst[(size_t)beh * N_ + n] = acc[0][i];
    }
  }
}

// ---- sparse attention v4 (round-10/11, passing — unchanged) ---------------
__global__ __launch_bounds__(256) void k_attn3(const float* q, const float* v,
                                               const unsigned short* Whb,
                                               const float* S, const int* fill,
                                               const int* colbuf, unsigned short* Hcatb) {
  int tid = threadIdx.x, lane = tid & 63, w = tid >> 6;
  int xcd = blockIdx.x & 7, j = blockIdx.x >> 3;
  int be = (xcd << 1) | (j & 1);
  int n = (j >> 1) * 4 + w;
  int b = be >> 1, e = be & 1;
  int L = fill[be * N_ + n];
  int Lc = (L > 64) ? 64 : L;
  int myc = (lane < Lc) ? colbuf[((size_t)(be * N_ + n)) * 64 + lane] : -1;
  int cct = 0, firstk = 64;
  for (int k = 0; k < Lc; ++k) {
    int ck = __shfl(myc, k, 64);
    if (myc >= 0 && ck == myc) { cct++; if (k < firstk) firstk = k; }
  }
  bool act = (lane < Lc) && (firstk == lane);
  unsigned long long mask = __ballot(act);
  int pos = __popcll(mask & ((1ull << lane) - 1ull));
  __shared__ int s_col[4][64];
  __shared__ int s_cnt[4][64];
  s_col[w][lane] = 0; s_cnt[w][lane] = 0;
  if (act) { s_col[w][pos] = myc; s_cnt[w][pos] = cct; }
  int Ld = __popcll(mask);
  int colc = s_col[w][lane];          // same-wave DS ordering: no barrier needed
  int cntc = s_cnt[w][lane];
  int eg = lane >> 4, g4 = (lane & 15) << 2;
  size_t outb = ((size_t)(b * N_ + n)) * C1 + e * G_ + g4;
  float fN = (float)(N_ - Ld);
#pragma unroll
  for (int h = 0; h < 4; ++h) {
    int beh = (be << 2) | h;
    float qn = q[beh * N_ + n];
    float sc = -1e30f;
    if (lane < Ld) {
      float t = qn * v[beh * N_ + colc] * (float)cntc;
      sc = (t >= 0.f) ? t : SLOPE_ * t;
    }
    float M = fmaxf(0.f, wmaxf(sc));
    float Ej = (lane < Ld) ? expf(sc - M) : 0.f;
    float sumE = wsumf(Ej);
    float em = expf(-M);
    float Z = fN * em + sumE;
    float wgt = (lane < Ld) ? (Ej - em) / Z : 0.f;
    float4 accv = make_float4(0.f, 0.f, 0.f, 0.f);
    if (eg == 0) {
      float4 s4 = *(const float4*)&S[(size_t)beh * G_ + g4];
      float sca = em / Z;
      accv.x = sca * s4.x; accv.y = sca * s4.y; accv.z = sca * s4.z; accv.w = sca * s4.w;
    }
    const unsigned short* WhB = Whb + (size_t)beh * N_ * G_;
    for (int k0 = 0; k0 < Ld; k0 += 4) {
      int kk = k0 + eg;
      float wk = __shfl(wgt, kk, 64);
      int ck = __shfl(colc, kk, 64);
      ushort4 xu = *(const ushort4*)&WhB[(size_t)ck * G_ + g4];
      accv.x += wk * b2f(xu.x); accv.y += wk * b2f(xu.y);
      accv.z += wk * b2f(xu.z); accv.w += wk * b2f(xu.w);
    }
    accv.x += __shfl_xor(accv.x, 16, 64); accv.y += __shfl_xor(accv.y, 16, 64);
    accv.z += __shfl_xor(accv.z, 16, 64); accv.w += __shfl_xor(accv.w, 16, 64);
    accv.x += __shfl_xor(accv.x, 32, 64); accv.y += __shfl_xor(accv.y, 32, 64);
    accv.z += __shfl_xor(accv.z, 32, 64); accv.w += __shfl_xor(accv.w, 32, 64);
    if (lane < 16) {
      ushort4 o;
      o.x = f2b(accv.x); o.y = f2b(accv.y); o.z = f2b(accv.z); o.w = f2b(accv.w);
      *(ushort4*)&Hcatb[outb + (size_t)h * (EC * G_)] = o;
    }
  }
}

// ---- mm1 (MFMA 16x32 tiles, 2048 waves): T4 = 0.5*relu(.)+0.5*X; stats1 ---
template <typename TX>
__device__ __forceinline__ void mm1_ep(f32x4* acc, const TX* X, float* T4,
                                       float* sum1, float* ssq1, int r0, int c0) {
  int lane = threadIdx.x & 63, q = lane >> 4, c15 = lane & 15;
#pragma unroll
  for (int nc = 0; nc < 2; ++nc) {
    int cc = c0 + nc * 16 + c15;
    float s = 0.f, s2 = 0.f;
#pragma unroll
    for (int i = 0; i < 4; ++i) {
      int rr = r0 + q * 4 + i;
      float o = fmaxf(acc[nc][i], 0.f);
      o = 0.5f * o + 0.5f * ldv(X, (size_t)rr * F_ + cc);
      T4[(size_t)rr * F_ + cc] = o;
      s += o; s2 += o * o;
    }
    s += __shfl_xor(s, 16, 64); s += __shfl_xor(s, 32, 64);
    s2 += __shfl_xor(s2, 16, 64); s2 += __shfl_xor(s2, 32, 64);
    if (lane < 16) {
      atomicAdd(&sum1[c0 + nc * 16 + lane], s);
      atomicAdd(&ssq1[c0 + nc * 16 + lane], s2);
    }
  }
}
__global__ __launch_bounds__(256) void k_mm1m(const unsigned short* Hcatb,
                                              const unsigned short* We1b, const void* X,
                                              float* T4, float* sum1, float* ssq1,
                                              const int* flag) {
  int w = threadIdx.x >> 6;
  int tile = blockIdx.x * 4 + w;                 // 2048 tiles
  int r0 = (tile >> 2) * 16, c0 = (tile & 3) * 32;
  f32x4 acc[2] = {{0,0,0,0},{0,0,0,0}};
  mfma_core_u<512, 2, unsigned short>(Hcatb, We1b, r0, c0, acc);
  if (*flag) mm1_ep<float>(acc, (const float*)X, T4, sum1, ssq1, r0, c0);
  else       mm1_ep<__hip_bfloat16>(acc, (const __hip_bfloat16*)X, T4, sum1, ssq1, r0, c0);
}

// ---- lin0 (MFMA 16x32, bn1 via LDS tables, 4096 waves): Z0; stats2 --------
__global__ __launch_bounds__(256) void k_lin0m(const float* T4, const float* sum1,
                                               const float* ssq1, const unsigned short* Wl0b,
                                               float* Z0, float* sum2, float* ssq2) {
  __shared__ float smean[128], srs[128];
  int tid = threadIdx.x;
  if (tid < 128) {
    float mean = sum1[tid] * (1.f / ROWS);
    float var = ssq1[tid] * (1.f / ROWS) - mean * mean;
    smean[tid] = mean; srs[tid] = rsqrtf(var + EPS_);
  }
  __syncthreads();
  int w = tid >> 6;
  int tile = blockIdx.x * 4 + w;                 // 4096 tiles
  int r0 = (tile >> 3) * 16, c0 = (tile & 7) * 32;
  f32x4 acc[2] = {{0,0,0,0},{0,0,0,0}};
  mfma_core_t2<128, 2, 1>(T4, smean, srs, Wl0b, r0, c0, acc);
  int lane = tid & 63, q = lane >> 4, c15 = lane & 15;
#pragma unroll
  for (int nc = 0; nc < 2; ++nc) {
    int cc = c0 + nc * 16 + c15;
    float s = 0.f, s2 = 0.f;
#pragma unroll
    for (int i = 0; i < 4; ++i) {
      int rr = r0 + q * 4 + i;
      float o = acc[nc][i];
      Z0[(size_t)rr * L0_ + cc] = o;
      s += o; s2 += o * o;
    }
    s += __shfl_xor(s, 16, 64); s += __shfl_xor(s, 32, 64);
    s2 += __shfl_xor(s2, 16, 64); s2 += __shfl_xor(s2, 32, 64);
    if (lane < 16) {
      atomicAdd(&sum2[c0 + nc * 16 + lane], s);
      atomicAdd(&ssq2[c0 + nc * 16 + lane], s2);
    }
  }
}

// ---- lin1 (MFMA 16x32, elu(bn2) via LDS tables, 2048 waves): T6; stats3 ---
__global__ __launch_bounds__(256) void k_lin1m(const float* Z0, const float* sum2,
                                               const float* ssq2, const unsigned short* Wl1b,
                                               const float* T4, const float* sum1,
                                               const float* ssq1,
                                               float* T6, float* sum3, float* ssq3) {
  __shared__ float smean[256], srs[256];
  int tid = threadIdx.x;
  {
    float mean = sum2[tid] * (1.f / ROWS);
    float var = ssq2[tid] * (1.f / ROWS) - mean * mean;
    smean[tid] = mean; srs[tid] = rsqrtf(var + EPS_);
  }
  __syncthreads();
  int w = tid >> 6;
  int tile = blockIdx.x * 4 + w;                 // 2048 tiles
  int r0 = (tile >> 2) * 16, c0 = (tile & 3) * 32;
  f32x4 acc[2] = {{0,0,0,0},{0,0,0,0}};
  mfma_core_t2<256, 2, 2>(Z0, smean, srs, Wl1b, r0, c0, acc);
  int lane = tid & 63, q = lane >> 4, c15 = lane & 15;
#pragma unroll
  for (int nc = 0; nc < 2; ++nc) {
    int cc = c0 + nc * 16 + c15;
    float mean = sum1[cc] * (1.f / ROWS);
    float var = ssq1[cc] * (1.f / ROWS) - mean * mean;
    float rs = rsqrtf(var + EPS_);
    float s = 0.f, s2 = 0.f;
#pragma unroll
    for (int i = 0; i < 4; ++i) {
      int rr = r0 + q * 4 + i;
      float o = acc[nc][i] + (T4[(size_t)rr * F_ + cc] - mean) * rs;
      T6[(size_t)rr * F_ + cc] = o;
      s += o; s2 += o * o;
    }
    s += __shfl_xor(s, 16, 64); s += __shfl_xor(s, 32, 64);
    s2 += __shfl_xor(s2, 16, 64); s2 += __shfl_xor(s2, 32, 64);
    if (lane < 16) {
      atomicAdd(&sum3[c0 + nc * 16 + lane], s);
      atomicAdd(&ssq3[c0 + nc * 16 + lane], s2);
    }
  }
}

__global__ void k_norm_out(const float* in, void* out, const float* sum, const float* ssq,
                           const int* flag) {
  int idx = (blockIdx.x * 256 + threadIdx.x) * 4;
  float4 xv = *(const float4*)&in[idx];
  float y[4]; float* xp = &xv.x;
#pragma unroll
  for (int j = 0; j < 4; ++j) {
    int c = (idx + j) & (F_ - 1);
    float mean = sum[c] * (1.f / ROWS);
    float var = ssq[c] * (1.f / ROWS) - mean * mean;
    y[j] = (xp[j] - mean) * rsqrtf(var + EPS_);
  }
  if (*flag) {
    *(float4*)&((float*)out)[idx] = make_float4(y[0], y[1], y[2], y[3]);
  } else {
    ushort4 o;
    o.x = f2b(y[0]); o.y = f2b(y[1]); o.z = f2b(y[2]); o.w = f2b(y[3]);
    *(ushort4*)&((__hip_bfloat16*)out)[idx] = o;
  }
}

// ---------------------------------------------------------------------------
extern "C" void kernel_launch(void* const* d_in, const int* in_sizes, int n_in,
                              void* d_out, int out_size, void* d_ws, size_t ws_size,
                              hipStream_t stream) {
  const int* A    = (const int*)d_in[0];
  const void* X   = d_in[1];
  const void* Ws  = d_in[2];
  const void* Wq  = d_in[3];
  const void* Wv  = d_in[4];
  const void* We1 = d_in[5];
  const void* Wl0 = d_in[6];
  const void* Wl1 = d_in[7];

  char* ws = (char*)d_ws;
  size_t off = 0;
  auto alloc = [&](size_t bytes) { size_t o = off; off += (bytes + 255) & ~(size_t)255; return o; };
  size_t o_fill   = alloc(16 * N_ * 4);            // zeroed
  size_t o_stats  = alloc(1024 * 4);               // zeroed
  size_t o_flag   = alloc(256);                    // zeroed
  size_t o_S      = alloc((size_t)64 * G_ * 4);    // zeroed (atomic accum)
  size_t zero_bytes = off;
  size_t o_colbuf = alloc((size_t)16 * N_ * 64 * 4);     // 4 MiB
  size_t o_q      = alloc((size_t)64 * N_ * 4);
  size_t o_v      = alloc((size_t)64 * N_ * 4);
  size_t o_Whb    = alloc((size_t)64 * N_ * G_ * 2);     // 8 MiB bf16
  size_t o_Hcatb  = alloc((size_t)ROWS * C1 * 2);        // 8 MiB bf16
  size_t o_T4     = alloc((size_t)ROWS * F_ * 4);        // f32
  size_t o_T6     = alloc((size_t)ROWS * F_ * 4);
  size_t o_Z0     = alloc((size_t)ROWS * L0_ * 4);       // f32
  size_t o_Wsb    = alloc((size_t)8 * G_ * F_ * 2);
  size_t o_We1b   = alloc((size_t)F_ * C1 * 2);
  size_t o_Wl1b   = alloc((size_t)F_ * L0_ * 2);
  size_t o_Wl0b   = alloc((size_t)L0_ * F_ * 2);
  size_t o_Wqvb   = alloc((size_t)16 * F_ * 2);

  int*   fill   = (int*)(ws + o_fill);
  float* stats  = (float*)(ws + o_stats);
  int*   flag   = (int*)(ws + o_flag);
  float* S      = (float*)(ws + o_S);
  int*   colbuf = (int*)(ws + o_colbuf);
  float* q      = (float*)(ws + o_q);
  float* v      = (float*)(ws + o_v);
  unsigned short* Whb   = (unsigned short*)(ws + o_Whb);
  unsigned short* Hcatb = (unsigned short*)(ws + o_Hcatb);
  float* T4     = (float*)(ws + o_T4);
  float* T6     = (float*)(ws + o_T6);
  float* Z0     = (float*)(ws + o_Z0);
  unsigned short* Wsb   = (unsigned short*)(ws + o_Wsb);
  unsigned short* We1b  = (unsigned short*)(ws + o_We1b);
  unsigned short* Wl1b  = (unsigned short*)(ws + o_Wl1b);
  unsigned short* Wl0b  = (unsigned short*)(ws + o_Wl0b);
  unsigned short* Wqvb  = (unsigned short*)(ws + o_Wqvb);
  float* sum1 = stats,       *ssq1 = stats + 128;
  float* sum2 = stats + 256, *ssq2 = stats + 512;
  float* sum3 = stats + 768, *ssq3 = stats + 896;

  hipMemsetAsync(ws, 0, zero_bytes, stream);

  k_prep<<<1536, 256, 0, stream>>>((const unsigned short*)X, flag, A, fill, colbuf);
  k_cvt2<<<776, 256, 0, stream>>>(Ws, We1, Wl1, Wl0, Wq, Wv,
                                  Wsb, We1b, Wl1b, Wl0b, Wqvb, flag);
  k_whm<<<dim3(ROWS / 64, 9), 256, 0, stream>>>(X, Wsb, Wqvb, Whb, S, q, v, flag);
  k_attn3<<<(16 * N_) / 4, 256, 0, stream>>>(q, v, Whb, S, fill, colbuf, Hcatb);
  k_mm1m<<<512, 256, 0, stream>>>(Hcatb, We1b, X, T4, sum1, ssq1, flag);
  k_lin0m<<<1024, 256, 0, stream>>>(T4, sum1, ssq1, Wl0b, Z0, sum2, ssq2);
  k_lin1m<<<512, 256, 0, stream>>>(Z0, sum2, ssq2, Wl1b, T4, sum1, ssq1,
                                   T6, sum3, ssq3);
  k_norm_out<<<(ROWS * F_) / 1024, 256, 0, stream>>>(T6, d_out, sum3, ssq3, flag);

  (void)in_sizes; (void)n_in; (void)out_size; (void)ws_size;
}